// Round 8
// baseline (211.357 us; speedup 1.0000x reference)
//
#include <hip/hip_runtime.h>

// Problem: BATCH=64, NFILT=512, T=1024, FFT over first 512 samples, 257 bins.
//   bc = (fc/Q)*0.5*sqrt(2pi)/FS ; n = t+1
//   y[b,f,t] = exp(-(bc*n)^2) * cos(2pi*fc/FS*n)
//   maxsq[f] = max_{b,k} |DFT_512(y[b,f,0:512])[k]|^2
//   out[b,f,t] = y[b,f,1023-t] * rsqrt(maxsq[f])
//
// R8: lane = batch. Per f, all 64 signals share kci/carrier/bins, so the
// n-loop and phasors are wave-uniform; each lane evaluates its own envelope
// and accumulates 8 bins (kci-3..kci+4; extended gap-free to bin 256 in the
// validated 407*bc merge zone; out-of-range k alias valid |X| by symmetry).
// Work = (chunk, bin-group) items over 8 single-wave blocks per f.
// 52M bin-samples vs R6's 283M; zero LDS; no hot-loop reductions.

#define BCOEF_K 7.8332133582218756e-05f  // 0.5*sqrt(2*pi)/16000
#define INV_FS  6.25e-05f                // 1/16000
#define TWO_PI  6.28318530717958647692f

#define NF 512
#define NB 64
#define GROUP 8                           // bins per item
#define MAXIT 16                          // item slots per f (worst case 14)
#define ITEM_STRIDE (GROUP * NB * 2)      // floats per item: 1024
#define F_STRIDE    (MAXIT * ITEM_STRIDE) // 16384 floats per f
#define B_OFFSET    (NF * F_STRIDE)       // partials: 8.4M floats = 33.6 MB

typedef float vf4 __attribute__((ext_vector_type(4)));

// cos(2*pi * n * fcn), phase reduced in revolutions -> native v_cos.
__device__ __forceinline__ float fast_carrier(float fcn, float n) {
  float rev = fcn * n;
  float fr  = rev - floorf(rev);
  return __cosf(TWO_PI * fr);
}
__device__ __forceinline__ float fast_env(float x) { return __expf(-x * x); }

// Shared per-f geometry: nchunk (64-sample chunks) and ngroups (8-bin groups).
// Deterministic: both kernels recompute identically from fc[f] and Q column.
__device__ __forceinline__ void f_geometry(float fcv, float bc_lane,
                                           int& nchunk, int& ngroups, int& kb) {
  float nsf = 4.0f / bc_lane;                     // per-lane nstar
  #pragma unroll
  for (int d = 32; d > 0; d >>= 1) nsf = fmaxf(nsf, __shfl_xor(nsf, d));
  const int nsamp = min(512, (int)nsf + 2);
  nchunk = (nsamp + 63) >> 6;                     // 1..8

  const float fcn = fcv * INV_FS;
  const int kci = (int)(fcn * 512.0f + 0.5f);
  kb = kci - 3;
  const float bcw = fcv * (BCOEF_K * 0.5f);       // worst bc in batch (Q=2)
  ngroups = 1;
  if (407.0f * bcw > (float)(512 - 2 * kci))      // validated merge criterion
    ngroups = ((256 - kb) >> 3) + 1;              // cover kb..>=256 gap-free
  if (nchunk * ngroups > MAXIT) ngroups = MAXIT / nchunk;  // defensive
}

// ---------------------------------------------------------------------------
// Kernel 1: grid = 512 f x 8 slots, block = 1 wave, lane = b. Each item
// (chunk c, group g) accumulates 8 complex bins over 64 samples; partials
// to ws[f][it][j][lane][re,im].
// ---------------------------------------------------------------------------
__global__ __launch_bounds__(64) void k_dft(const float* __restrict__ Q,
                                            const float* __restrict__ fc,
                                            float* __restrict__ ws) {
  const int s    = blockIdx.x & 7;
  const int f    = blockIdx.x >> 3;
  const int lane = threadIdx.x;          // = b

  const float fcv = fc[f];
  const float q   = Q[lane * NF + f];
  const float bc  = (fcv / q) * BCOEF_K;
  const float fcn = fcv * INV_FS;

  int nchunk, ngroups, kb;
  f_geometry(fcv, bc, nchunk, ngroups, kb);
  const int nitems = nchunk * ngroups;

  for (int it = s; it < nitems; it += 8) {
    const int c  = it % nchunk;
    const int g  = it / nchunk;
    const int k0 = kb + (g << 3);
    const int n0 = (c << 6) + 1;

    // phasors p_j = e^{-i*2pi*k_j*n0/512}, rotators d_j = e^{-i*2pi*k_j/512}
    // (k_j*n0 < 2^24 and /512 is dyadic -> phase reduction exact)
    float pre[GROUP], pim[GROUP], dre[GROUP], dim[GROUP];
    #pragma unroll
    for (int j = 0; j < GROUP; ++j) {
      const float kj = (float)(k0 + j);
      float rp = kj * (float)n0 * (1.0f / 512.0f);
      rp -= floorf(rp);
      pre[j] = __cosf(TWO_PI * rp);
      pim[j] = -__sinf(TWO_PI * rp);
      float rd = kj * (1.0f / 512.0f);
      rd -= floorf(rd);
      dre[j] = __cosf(TWO_PI * rd);
      dim[j] = -__sinf(TWO_PI * rd);
    }

    float Xre[GROUP], Xim[GROUP];
    #pragma unroll
    for (int j = 0; j < GROUP; ++j) { Xre[j] = 0.0f; Xim[j] = 0.0f; }

    for (int i = 0; i < 64; ++i) {       // wave-uniform n loop
      const float nf = (float)(n0 + i);
      const float y  = fast_env(bc * nf) * fast_carrier(fcn, nf);
      #pragma unroll
      for (int j = 0; j < GROUP; ++j) {
        Xre[j] = fmaf(y, pre[j], Xre[j]);
        Xim[j] = fmaf(y, pim[j], Xim[j]);
        const float t = pre[j] * dre[j] - pim[j] * dim[j];
        pim[j] = fmaf(pre[j], dim[j], pim[j] * dre[j]);
        pre[j] = t;
      }
    }

    float* base = ws + (size_t)(f * MAXIT + it) * ITEM_STRIDE + lane * 2;
    #pragma unroll
    for (int j = 0; j < GROUP; ++j) {
      base[j * NB * 2]     = Xre[j];
      base[j * NB * 2 + 1] = Xim[j];
    }
  }
}

// ---------------------------------------------------------------------------
// Kernel 2: 512 single-wave blocks, lane = b. Sum chunk partials per bin,
// magnitude, max over bins -> ws[B_OFFSET + f*64 + b].
// ---------------------------------------------------------------------------
__global__ __launch_bounds__(64) void k_reduce(const float* __restrict__ Q,
                                               const float* __restrict__ fc,
                                               float* __restrict__ ws) {
  const int f    = blockIdx.x;
  const int lane = threadIdx.x;          // = b

  const float fcv = fc[f];
  const float q   = Q[lane * NF + f];
  const float bc  = (fcv / q) * BCOEF_K;

  int nchunk, ngroups, kb;
  f_geometry(fcv, bc, nchunk, ngroups, kb);

  float mx = 0.0f;
  for (int g = 0; g < ngroups; ++g) {
    for (int j = 0; j < GROUP; ++j) {
      float re = 0.0f, im = 0.0f;
      for (int c = 0; c < nchunk; ++c) {
        const float* p = ws + (size_t)(f * MAXIT + g * nchunk + c) * ITEM_STRIDE
                         + j * NB * 2 + lane * 2;
        re += p[0];
        im += p[1];
      }
      mx = fmaxf(mx, fmaf(re, re, im * im));
    }
  }
  ws[B_OFFSET + f * NB + lane] = mx;
}

// ---------------------------------------------------------------------------
// Kernel 3: one block per (b,f) row. Wave loads the 64 per-batch maxes for f,
// shfl-max; thread tid writes float4 at t0=4*tid, n = 1024 - t (flip),
// scaled by rsqrt(maxsq). Dead tail stores zeros. Nontemporal stores.
// ---------------------------------------------------------------------------
__global__ __launch_bounds__(256) void k_write(const float* __restrict__ Q,
                                               const float* __restrict__ fc,
                                               const float* __restrict__ ws,
                                               float* __restrict__ out) {
  const int blk = blockIdx.x;      // bb*512 + f
  const int f   = blk & 511;
  const int bb  = blk >> 9;
  const int tid = threadIdx.x;

  float mx = ws[B_OFFSET + f * NB + (tid & 63)];
  #pragma unroll
  for (int d = 32; d > 0; d >>= 1) mx = fmaxf(mx, __shfl_xor(mx, d));

  const float fcv = fc[f];
  const float q   = Q[bb * NF + f];
  const float bc  = (fcv / q) * BCOEF_K;
  const float fcn = fcv * INV_FS;
  const float nstar = 4.0f / bc;

  const int t0 = tid * 4;
  vf4 r = {0.0f, 0.0f, 0.0f, 0.0f};
  if ((float)(1021 - t0) <= nstar) {
    const float inv = rsqrtf(mx);
    const float n0 = (float)(1024 - t0);
    const float n1 = (float)(1023 - t0);
    const float n2 = (float)(1022 - t0);
    const float n3 = (float)(1021 - t0);
    r.x = fast_env(bc * n0) * fast_carrier(fcn, n0) * inv;
    r.y = fast_env(bc * n1) * fast_carrier(fcn, n1) * inv;
    r.z = fast_env(bc * n2) * fast_carrier(fcn, n2) * inv;
    r.w = fast_env(bc * n3) * fast_carrier(fcn, n3) * inv;
  }
  __builtin_nontemporal_store(r, &((vf4*)out)[blk * 256 + tid]);
}

// ---------------------------------------------------------------------------
extern "C" void kernel_launch(void* const* d_in, const int* in_sizes, int n_in,
                              void* d_out, int out_size, void* d_ws, size_t ws_size,
                              hipStream_t stream) {
  const float* Q  = (const float*)d_in[0];   // [64, 512] f32
  const float* fc = (const float*)d_in[1];   // [512] f32
  float* out      = (float*)d_out;           // [64, 512, 1024] f32
  float* ws       = (float*)d_ws;            // partials + per-(f,b) maxes

  k_dft   <<<NF * 8,  64,  0, stream>>>(Q, fc, ws);
  k_reduce<<<NF,      64,  0, stream>>>(Q, fc, ws);
  k_write <<<64 * NF, 256, 0, stream>>>(Q, fc, ws, out);
}

// Round 9
// 171.651 us; speedup vs baseline: 1.2313x; 1.2313x over previous
//
#include <hip/hip_runtime.h>

// Problem: BATCH=64, NFILT=512, T=1024, FFT over first 512 samples, 257 bins.
//   bc = (fc/Q)*0.5*sqrt(2pi)/FS ; n = t+1
//   y[b,f,t] = exp(-(bc*n)^2) * cos(2pi*fc/FS*n)
//   maxsq[f] = max_{b,k} |DFT_512(y[b,f,0:512])[k]|^2
//   out[b,f,t] = y[b,f,1023-t] * rsqrt(maxsq[f])
//
// R9 = R6 architecture (best, 164.7us) + two cuts:
// (1) Q pruning: all b of a filter share kc => same fractional bin offset.
//     Peak bin value v(bc) is strictly decreasing in bc for bc>0.00434, so
//     the batch max lives in {bc <= 1.3*bc_min}; competitors are >=20%
//     smaller (worst case 0.80 ratio incl. corrections). Filters with
//     fc < 700 Hz (where v(bc) can be non-monotone) evaluate all 64.
//     => 0.34x the Goertzel work, evaluated signals bit-identical to R6.
// (2) k_main also carries 32768 zero-blocks that store the dead prefix of
//     each output row (pure HBM, overlaps maxfft's VALU/DS); k_live then
//     writes only the ~22 MB live region.

#define BCOEF_K 7.8332133582218756e-05f  // 0.5*sqrt(2*pi)/16000
#define INV_FS  6.25e-05f                // 1/16000
#define TWO_PI  6.28318530717958647692f
#define PI_F    3.14159265358979323846f
#define SIGK_K  115.2309f                // sqrt(2)*512/(2*pi)
#define KAPPA   1.3f                     // pruning safety factor
#define FULL_FC 700.0f                   // below this fc, evaluate all 64 b

typedef float vf4 __attribute__((ext_vector_type(4)));

// cos(2*pi * n * fcn), phase reduced in revolutions -> native v_cos.
__device__ __forceinline__ float fast_carrier(float fcn, float n) {
  float rev = fcn * n;
  float fr  = rev - floorf(rev);
  return __cosf(TWO_PI * fr);
}
__device__ __forceinline__ float fast_env(float x) { return __expf(-x * x); }

// ---------------------------------------------------------------------------
// Kernel 1: blocks [0,8192): maxfft, 4 waves/block, wave = signal (bb,f),
// R6 logic + Q-candidate pruning. Blocks [8192, 8192+32768): zero-store the
// dead prefix of output row (blk-8192). The zero blocks are store-only and
// overlap the maxfft blocks' VALU/DS work.
// ---------------------------------------------------------------------------
__global__ __launch_bounds__(256) void k_main(const float* __restrict__ Q,
                                              const float* __restrict__ fc,
                                              float* __restrict__ ws,
                                              float* __restrict__ out) {
  const int blk = blockIdx.x;
  const int tid = threadIdx.x;

  if (blk >= 8192) {
    // ---- zero part: row = bb*512 + f, store zeros where quad is dead ----
    const int row = blk - 8192;
    const int f   = row & 511;
    const int bb  = row >> 9;
    const float fcv = fc[f];
    const float q   = Q[bb * 512 + f];
    const float bc  = (fcv / q) * BCOEF_K;
    const float nstar = 4.0f / bc;
    const int t0 = tid * 4;
    if ((float)(1021 - t0) > nstar) {      // exact complement of k_live
      vf4 z = {0.0f, 0.0f, 0.0f, 0.0f};
      __builtin_nontemporal_store(z, &((vf4*)out)[row * 256 + tid]);
    }
    return;
  }

  // ---- maxfft part (R6 machinery + pruning) ----
  const int w    = tid >> 6;           // wave 0..3
  const int lane = tid & 63;
  const int sig  = blk * 4 + w;        // bb*512 + f
  const int f    = sig & 511;
  const int bb   = sig >> 9;

  __shared__ __align__(16) float ybuf[4][512];

  const float fcv = fc[f];
  const float q   = Q[bb * 512 + f];
  const float bc  = (fcv / q) * BCOEF_K;
  const float fcn = fcv * INV_FS;

  // --- pruning: candidate iff bc <= KAPPA * bc_min(batch) or low-fc ---
  float qq = Q[lane * 512 + f];        // lane = batch index (L2-hot gather)
  #pragma unroll
  for (int d = 32; d > 0; d >>= 1) qq = fmaxf(qq, __shfl_xor(qq, d));
  const float bcmin = (fcv / qq) * BCOEF_K;  // qq = max Q in batch
  if (fcv >= FULL_FC && bc > KAPPA * bcmin) {
    if (lane == 0) ws[f * 64 + bb] = 0.0f;   // provably below batch max
    return;                                   // wave-uniform exit
  }

  // --- effective length: env < e^-16 beyond nstar = 4/bc (wave-uniform) ---
  const float nstar = 4.0f / bc;
  const int   N_eff = (nstar >= 510.0f) ? 512 : ((int)nstar + 2);
  const int   jmax  = (N_eff + 3) >> 2;      // float4 groups Goertzel reads
  const int   n4    = jmax << 2;             // samples to generate

  // --- lane-strided generation: lane writes samples lane, lane+64, ... ---
  float* yw = &ybuf[w][0];
  const int nit_g = (n4 + 63) >> 6;          // 1..8, wave-uniform
  for (int r = 0; r < nit_g; ++r) {
    const int idx = (r << 6) + lane;         // t index; n = idx+1
    const float n = (float)(idx + 1);
    const float v = fast_env(bc * n) * fast_carrier(fcn, n);
    if (idx < n4) yw[idx] = v;               // masked tail store
  }
  // Wave-local write->read ordering (row is private to this wave).
  asm volatile("s_waitcnt lgkmcnt(0)" ::: "memory");

  // --- spectral-peak window (R6 logic, wave-uniform) ---
  const int kci  = (int)(fcn * 512.0f + 0.5f);
  const int W    = (int)(2.0f * (bc * SIGK_K)) + 6;
  const int k_lo = max(0, kci - W);
  const int k_hi = min(256, kci + W);
  const int nit  = ((k_hi - k_lo) >> 6) + 1;  // 1..5 iterations

  const float4* y4 = (const float4*)yw;      // wave-uniform broadcasts
  float mx = 0.0f;
  for (int it = 0; it < nit; ++it) {         // wave-uniform trip count
    const int   k = min(k_lo + (it << 6) + lane, k_hi);  // dup bins harmless
    const float c = 2.0f * cosf((float)k * (PI_F / 256.0f));
    float s1 = 0.0f, s2 = 0.0f;
    #pragma unroll 4
    for (int j = 0; j < jmax; ++j) {         // wave-uniform trip count
      const float4 x = y4[j];
      float s;
      s = fmaf(c, s1, x.x - s2); s2 = s1; s1 = s;
      s = fmaf(c, s1, x.y - s2); s2 = s1; s1 = s;
      s = fmaf(c, s1, x.z - s2); s2 = s1; s1 = s;
      s = fmaf(c, s1, x.w - s2); s2 = s1; s1 = s;
    }
    mx = fmaxf(mx, fmaf(s1, s1, fmaf(s2, s2, -(c * s1 * s2))));
  }

  #pragma unroll
  for (int d = 32; d > 0; d >>= 1) mx = fmaxf(mx, __shfl_xor(mx, d));
  if (lane == 0) ws[f * 64 + bb] = mx;       // per-signal result, no atomic
}

// ---------------------------------------------------------------------------
// Kernel 2: one block per (b,f) row. Wave loads the 64 per-batch results for
// f, shfl-max; thread tid writes its float4 ONLY if alive (dead prefix was
// zeroed by k_main). n = 1024 - t (flip), scaled by rsqrt(maxsq).
// ---------------------------------------------------------------------------
__global__ __launch_bounds__(256) void k_live(const float* __restrict__ Q,
                                              const float* __restrict__ fc,
                                              const float* __restrict__ ws,
                                              float* __restrict__ out) {
  const int blk = blockIdx.x;      // bb*512 + f
  const int f   = blk & 511;
  const int bb  = blk >> 9;
  const int tid = threadIdx.x;

  // max over batch of |X|^2 for this f (pruned entries are 0.0 -> harmless)
  float mx = ws[f * 64 + (tid & 63)];
  #pragma unroll
  for (int d = 32; d > 0; d >>= 1) mx = fmaxf(mx, __shfl_xor(mx, d));

  const float fcv = fc[f];
  const float q   = Q[bb * 512 + f];
  const float bc  = (fcv / q) * BCOEF_K;
  const float fcn = fcv * INV_FS;
  const float nstar = 4.0f / bc;

  const int t0 = tid * 4;
  // quad covers n = 1021-t0 .. 1024-t0; live iff smallest n <= nstar
  if ((float)(1021 - t0) <= nstar) {         // exact complement of zero part
    const float inv = rsqrtf(mx);
    const float n0 = (float)(1024 - t0);
    const float n1 = (float)(1023 - t0);
    const float n2 = (float)(1022 - t0);
    const float n3 = (float)(1021 - t0);
    vf4 r;
    r.x = fast_env(bc * n0) * fast_carrier(fcn, n0) * inv;
    r.y = fast_env(bc * n1) * fast_carrier(fcn, n1) * inv;
    r.z = fast_env(bc * n2) * fast_carrier(fcn, n2) * inv;
    r.w = fast_env(bc * n3) * fast_carrier(fcn, n3) * inv;
    __builtin_nontemporal_store(r, &((vf4*)out)[blk * 256 + tid]);
  }
}

// ---------------------------------------------------------------------------
extern "C" void kernel_launch(void* const* d_in, const int* in_sizes, int n_in,
                              void* d_out, int out_size, void* d_ws, size_t ws_size,
                              hipStream_t stream) {
  const float* Q  = (const float*)d_in[0];   // [64, 512] f32
  const float* fc = (const float*)d_in[1];   // [512] f32
  float* out      = (float*)d_out;           // [64, 512, 1024] f32
  float* ws       = (float*)d_ws;            // [512*64] per-signal |X|^2 max

  k_main<<<8192 + 64 * 512, 256, 0, stream>>>(Q, fc, ws, out);
  k_live<<<64 * 512,        256, 0, stream>>>(Q, fc, ws, out);
}

// Round 10
// 162.180 us; speedup vs baseline: 1.3032x; 1.0584x over previous
//
#include <hip/hip_runtime.h>

// Problem: BATCH=64, NFILT=512, T=1024, FFT over first 512 samples, 257 bins.
//   bc = (fc/Q)*0.5*sqrt(2pi)/FS ; n = t+1
//   y[b,f,t] = exp(-(bc*n)^2) * cos(2pi*fc/FS*n)
//   maxsq[f] = max_{b,k} |DFT_512(y[b,f,0:512])[k]|^2
//   out[b,f,t] = y[b,f,1023-t] * rsqrt(maxsq[f])
//
// R10 = exact R6 (best known, 164.7us) + Q-candidate pruning ONLY.
//   Pruning: all b of a filter share kc => same fractional bin offset.
//   Peak-bin value v(bc) is strictly decreasing in bc for bc > 0.00434,
//   so the batch max lives in {bc <= 1.3*bc_min}; competitors >= 20% down.
//   Filters with fc < 700 Hz evaluate all 64 (non-monotone corner).
//   Surviving waves are bit-identical to R6 => absmax unchanged.

#define BCOEF_K 7.8332133582218756e-05f  // 0.5*sqrt(2*pi)/16000
#define INV_FS  6.25e-05f                // 1/16000
#define TWO_PI  6.28318530717958647692f
#define PI_F    3.14159265358979323846f
#define SIGK_K  115.2309f                // sqrt(2)*512/(2*pi)
#define KAPPA   1.3f                     // pruning safety factor
#define FULL_FC 700.0f                   // below this fc, evaluate all 64 b

typedef float vf4 __attribute__((ext_vector_type(4)));  // nt-store compatible

// cos(2*pi * n * fcn), phase reduced in revolutions -> native v_cos.
__device__ __forceinline__ float fast_carrier(float fcn, float n) {
  float rev = fcn * n;
  float fr  = rev - floorf(rev);
  return __cosf(TWO_PI * fr);
}
__device__ __forceinline__ float fast_env(float x) { return __expf(-x * x); }

// ---------------------------------------------------------------------------
// Kernel 1: block = 4 independent waves; wave w owns signal sig = blk*4+w.
// Wave generates its truncated signal into its private LDS row (lane-strided),
// then one windowed Goertzel pass. Result -> ws[f*64 + bb]. No barriers.
// ---------------------------------------------------------------------------
__global__ __launch_bounds__(256) void k_maxfft(const float* __restrict__ Q,
                                                const float* __restrict__ fc,
                                                float* __restrict__ ws) {
  const int tid  = threadIdx.x;
  const int w    = tid >> 6;           // wave 0..3
  const int lane = tid & 63;
  const int sig  = blockIdx.x * 4 + w; // bb*512 + f
  const int f    = sig & 511;
  const int bb   = sig >> 9;

  __shared__ __align__(16) float ybuf[4][512];

  const float fcv = fc[f];
  const float q   = Q[bb * 512 + f];
  const float bc  = (fcv / q) * BCOEF_K;
  const float fcn = fcv * INV_FS;

  // --- pruning: candidate iff bc <= KAPPA * bc_min(batch) or low-fc ---
  float qq = Q[lane * 512 + f];        // lane = batch index (Q is L2-hot)
  #pragma unroll
  for (int d = 32; d > 0; d >>= 1) qq = fmaxf(qq, __shfl_xor(qq, d));
  if (fcv >= FULL_FC && bc * qq > KAPPA * fcv * BCOEF_K) {
    if (lane == 0) ws[f * 64 + bb] = 0.0f;   // provably below batch max
    return;                                   // wave-uniform exit
  }

  // --- effective length: env < e^-16 beyond nstar = 4/bc (wave-uniform) ---
  const float nstar = 4.0f / bc;
  const int   N_eff = (nstar >= 510.0f) ? 512 : ((int)nstar + 2);
  const int   jmax  = (N_eff + 3) >> 2;      // float4 groups Goertzel reads
  const int   n4    = jmax << 2;             // samples to generate

  // --- lane-strided generation: lane writes samples lane, lane+64, ... ---
  float* yw = &ybuf[w][0];
  const int nit_g = (n4 + 63) >> 6;          // 1..8, wave-uniform
  for (int r = 0; r < nit_g; ++r) {
    const int idx = (r << 6) + lane;         // t index; n = idx+1
    const float n = (float)(idx + 1);
    const float v = fast_env(bc * n) * fast_carrier(fcn, n);
    if (idx < n4) yw[idx] = v;               // masked tail store
  }
  // Wave-local write->read ordering (row is private to this wave).
  asm volatile("s_waitcnt lgkmcnt(0)" ::: "memory");

  // --- spectral-peak window (wave-uniform) ---
  const int kci  = (int)(fcn * 512.0f + 0.5f);
  const int W    = (int)(2.0f * (bc * SIGK_K)) + 6;
  const int k_lo = max(0, kci - W);
  const int k_hi = min(256, kci + W);
  const int nit  = ((k_hi - k_lo) >> 6) + 1;  // 1..5 iterations

  const float4* y4 = (const float4*)yw;      // wave-uniform broadcasts
  float mx = 0.0f;
  for (int it = 0; it < nit; ++it) {         // wave-uniform trip count
    const int   k = min(k_lo + (it << 6) + lane, k_hi);  // dup bins harmless
    const float c = 2.0f * cosf((float)k * (PI_F / 256.0f));
    float s1 = 0.0f, s2 = 0.0f;
    #pragma unroll 4
    for (int j = 0; j < jmax; ++j) {         // wave-uniform trip count
      const float4 x = y4[j];
      float s;
      s = fmaf(c, s1, x.x - s2); s2 = s1; s1 = s;
      s = fmaf(c, s1, x.y - s2); s2 = s1; s1 = s;
      s = fmaf(c, s1, x.z - s2); s2 = s1; s1 = s;
      s = fmaf(c, s1, x.w - s2); s2 = s1; s1 = s;
    }
    mx = fmaxf(mx, fmaf(s1, s1, fmaf(s2, s2, -(c * s1 * s2))));
  }

  #pragma unroll
  for (int d = 32; d > 0; d >>= 1) mx = fmaxf(mx, __shfl_xor(mx, d));
  if (lane == 0) ws[f * 64 + bb] = mx;       // per-signal result, no atomic
}

// ---------------------------------------------------------------------------
// Kernel 2: one block per (b,f) row. Wave loads the 64 per-batch results for
// f (pruned entries are 0.0, harmless under max), shfl-max; thread tid writes
// float4 at t0=4*tid, n = 1024 - t (flip), scaled by rsqrt(maxsq).
// Dead tail stores zeros. Nontemporal streaming stores. (Exact R6 k_write.)
// ---------------------------------------------------------------------------
__global__ __launch_bounds__(256) void k_write(const float* __restrict__ Q,
                                               const float* __restrict__ fc,
                                               const float* __restrict__ ws,
                                               float* __restrict__ out) {
  const int blk = blockIdx.x;      // bb*512 + f
  const int f   = blk & 511;
  const int bb  = blk >> 9;
  const int tid = threadIdx.x;

  float mx = ws[f * 64 + (tid & 63)];
  #pragma unroll
  for (int d = 32; d > 0; d >>= 1) mx = fmaxf(mx, __shfl_xor(mx, d));

  const float fcv = fc[f];
  const float q   = Q[bb * 512 + f];
  const float bc  = (fcv / q) * BCOEF_K;
  const float fcn = fcv * INV_FS;
  const float nstar = 4.0f / bc;

  const int t0 = tid * 4;
  vf4 r = {0.0f, 0.0f, 0.0f, 0.0f};
  // quad covers n = 1021-t0 .. 1024-t0; all dead iff smallest n > nstar
  if ((float)(1021 - t0) <= nstar) {
    const float inv = rsqrtf(mx);
    const float n0 = (float)(1024 - t0);
    const float n1 = (float)(1023 - t0);
    const float n2 = (float)(1022 - t0);
    const float n3 = (float)(1021 - t0);
    r.x = fast_env(bc * n0) * fast_carrier(fcn, n0) * inv;
    r.y = fast_env(bc * n1) * fast_carrier(fcn, n1) * inv;
    r.z = fast_env(bc * n2) * fast_carrier(fcn, n2) * inv;
    r.w = fast_env(bc * n3) * fast_carrier(fcn, n3) * inv;
  }
  __builtin_nontemporal_store(r, &((vf4*)out)[blk * 256 + tid]);
}

// ---------------------------------------------------------------------------
extern "C" void kernel_launch(void* const* d_in, const int* in_sizes, int n_in,
                              void* d_out, int out_size, void* d_ws, size_t ws_size,
                              hipStream_t stream) {
  const float* Q  = (const float*)d_in[0];   // [64, 512] f32
  const float* fc = (const float*)d_in[1];   // [512] f32
  float* out      = (float*)d_out;           // [64, 512, 1024] f32
  float* ws       = (float*)d_ws;            // [512*64] per-signal |X|^2 max

  k_maxfft<<<64 * 512 / 4, 256, 0, stream>>>(Q, fc, ws);
  k_write <<<64 * 512,     256, 0, stream>>>(Q, fc, ws, out);
}